// Round 3
// baseline (167.485 us; speedup 1.0000x reference)
//
#include <hip/hip_runtime.h>

#define N_NODES 16384
#define NE 524288
#define KDIM 1152          // IN*NG + IN
#define KSTEPS 36          // 1152 / 32

typedef unsigned int uint32;
typedef unsigned short ushort;
typedef __attribute__((ext_vector_type(8))) short bf16x8;
typedef __attribute__((ext_vector_type(4))) float f32x4;

__device__ __forceinline__ ushort f2bf(float f) {
    unsigned u = __float_as_uint(f);
    unsigned r = (u + 0x7fffu + ((u >> 16) & 1u)) >> 16;
    return (ushort)r;
}
__device__ __forceinline__ float bflo(uint32 u) {
    return __uint_as_float(u << 16);
}
__device__ __forceinline__ float bfhi(uint32 u) {
    return __uint_as_float(u & 0xffff0000u);
}

// ---------------- weight pack into MFMA B-fragment order (bf16) ----------------
__global__ __launch_bounds__(256) void transw_kernel(
    const float* __restrict__ sw, const float* __restrict__ bw,
    ushort* __restrict__ Wp) {
    int idx = blockIdx.x * 256 + threadIdx.x;      // 0 .. 147455
    int i  = idx & 7;
    int l  = (idx >> 3) & 63;
    int ct = (idx >> 9) & 7;
    int kk = idx >> 12;
    int k   = kk * 32 + ((l >> 4) << 3) + i;
    int col = ct * 16 + (l & 15);
    float v = (k < 1024) ? sw[col * 1024 + k] : bw[col * 128 + (k - 1024)];
    Wp[idx] = f2bf(v);
}

// ---------------- degree histogram (with duplicate edges) ----------------
__global__ __launch_bounds__(256) void hist_kernel(
    const int* __restrict__ ei, int* __restrict__ cnt) {
    int e = blockIdx.x * 256 + threadIdx.x;
    int a = ei[e];
    int b = ei[NE + e];
    atomicAdd(cnt + a, 1);
    atomicAdd(cnt + b, 1);
}

// ---------------- single-block exclusive scan over 16384 counts ----------------
__global__ __launch_bounds__(1024) void scan_kernel(
    const int* __restrict__ cnt, int* __restrict__ start) {
    __shared__ int ps[1024];
    const int t = threadIdx.x;
    int loc[16];
    const int4* c4 = (const int4*)cnt + t * 4;
    int sum = 0;
#pragma unroll
    for (int q = 0; q < 4; ++q) {
        int4 w = c4[q];
        loc[q * 4 + 0] = w.x; loc[q * 4 + 1] = w.y;
        loc[q * 4 + 2] = w.z; loc[q * 4 + 3] = w.w;
    }
#pragma unroll
    for (int q = 0; q < 16; ++q) { int tmp = loc[q]; loc[q] = sum; sum += tmp; }
    ps[t] = sum;
    __syncthreads();
    for (int off = 1; off < 1024; off <<= 1) {
        int v = ps[t];
        int add = (t >= off) ? ps[t - off] : 0;
        __syncthreads();
        ps[t] = v + add;
        __syncthreads();
    }
    int base = (t == 0) ? 0 : ps[t - 1];
    int4* s4 = (int4*)start + t * 4;
#pragma unroll
    for (int q = 0; q < 4; ++q) {
        int4 w;
        w.x = base + loc[q * 4 + 0]; w.y = base + loc[q * 4 + 1];
        w.z = base + loc[q * 4 + 2]; w.w = base + loc[q * 4 + 3];
        s4[q] = w;
    }
    if (t == 1023) start[N_NODES] = ps[1023];
}

// ---------------- CSR bucket fill (consumes cnt down to 0) ----------------
__global__ __launch_bounds__(256) void fill_kernel(
    const int* __restrict__ ei, const int* __restrict__ start,
    int* __restrict__ cnt, int* __restrict__ adj) {
    int e = blockIdx.x * 256 + threadIdx.x;
    int a = ei[e];
    int b = ei[NE + e];
    int pa = start[a] + atomicSub(cnt + a, 1) - 1;
    adj[pa] = b;
    int pb = start[b] + atomicSub(cnt + b, 1) - 1;
    adj[pb] = a;
}

// ---------------- dedup'd degree -> dis = rsqrt(deg), via LDS bitmask ----------------
// 256 threads = 4 waves, 1 wave per node
__global__ __launch_bounds__(256) void deg_kernel(
    const int* __restrict__ start, const int* __restrict__ adj,
    float* __restrict__ dis) {
    __shared__ uint32 mask[4][512];
    const int t = threadIdx.x;
    const int lane = t & 63;
    const int w = t >> 6;
    const int node = blockIdx.x * 4 + w;
#pragma unroll
    for (int q = 0; q < 8; ++q) mask[w][lane + 64 * q] = 0;
    __syncthreads();
    const int s0 = start[node];
    const int len = start[node + 1] - s0;
    for (int p = lane; p < len; p += 64) {
        int j = adj[s0 + p];
        atomicOr(&mask[w][j >> 5], 1u << (j & 31));
    }
    __syncthreads();
    int s = 0;
#pragma unroll
    for (int q = 0; q < 8; ++q) s += __popc(mask[w][lane + 64 * q]);
#pragma unroll
    for (int o = 32; o; o >>= 1) s += __shfl_xor(s, o);
    if (lane == 0) dis[node] = rsqrtf((float)s);
}

// ---------------- fused FastKAN support (bf16 MFMA), pre-scaled by dis ----------------
__global__ __launch_bounds__(256) void support_kernel(
    const float* __restrict__ x, const float* __restrict__ gamma,
    const float* __restrict__ beta, const ushort* __restrict__ Wp,
    const float* __restrict__ base_b, const float* __restrict__ dis,
    ushort* __restrict__ Ssc) {
    __shared__ ushort Bs[16][KDIM];                 // 36864 B
    const int t = threadIdx.x;
    const int lane = t & 63;
    const int w = t >> 6;
    const int nodeBase = blockIdx.x * 16;

    const float g0 = gamma[lane], g1 = gamma[lane + 64];
    const float be0 = beta[lane], be1 = beta[lane + 64];

    for (int n = w * 4; n < w * 4 + 4; ++n) {
        const int row = nodeBase + n;
        float f0 = x[(size_t)row * 128 + lane];
        float f1 = x[(size_t)row * 128 + lane + 64];
        float s = f0 + f1;
#pragma unroll
        for (int o = 32; o; o >>= 1) s += __shfl_xor(s, o);
        float mu = s * 0.0078125f;
        float d0 = f0 - mu, d1 = f1 - mu;
        float v = d0 * d0 + d1 * d1;
#pragma unroll
        for (int o = 32; o; o >>= 1) v += __shfl_xor(v, o);
        float rstd = rsqrtf(v * 0.0078125f + 1e-5f);
        float h0 = d0 * rstd * g0 + be0;
        float h1 = d1 * rstd * g1 + be1;
        ushort pk0[8] __attribute__((aligned(16)));
        ushort pk1[8] __attribute__((aligned(16)));
#pragma unroll
        for (int g = 0; g < 8; ++g) {
            float gv = -2.0f + (float)g * (4.0f / 7.0f);
            float z0 = (h0 - gv) * 1.75f;
            float z1 = (h1 - gv) * 1.75f;
            pk0[g] = f2bf(__expf(-z0 * z0));
            pk1[g] = f2bf(__expf(-z1 * z1));
        }
        *reinterpret_cast<uint4*>(&Bs[n][lane * 8]) =
            *reinterpret_cast<const uint4*>(pk0);
        *reinterpret_cast<uint4*>(&Bs[n][(lane + 64) * 8]) =
            *reinterpret_cast<const uint4*>(pk1);
        Bs[n][1024 + lane]      = f2bf(f0 / (1.0f + __expf(-f0)));
        Bs[n][1024 + lane + 64] = f2bf(f1 / (1.0f + __expf(-f1)));
    }
    __syncthreads();

    const int ct0 = w * 2;
    f32x4 acc0 = {0.f, 0.f, 0.f, 0.f};
    f32x4 acc1 = {0.f, 0.f, 0.f, 0.f};
    const ushort* ArowBase = &Bs[lane & 15][(lane >> 4) * 8];
    const bf16x8* Wv = (const bf16x8*)Wp;
#pragma unroll 4
    for (int kk = 0; kk < KSTEPS; ++kk) {
        bf16x8 a = *reinterpret_cast<const bf16x8*>(ArowBase + kk * 32);
        bf16x8 b0 = Wv[(size_t)(kk * 8 + ct0) * 64 + lane];
        bf16x8 b1 = Wv[(size_t)(kk * 8 + ct0 + 1) * 64 + lane];
        acc0 = __builtin_amdgcn_mfma_f32_16x16x32_bf16(a, b0, acc0, 0, 0, 0);
        acc1 = __builtin_amdgcn_mfma_f32_16x16x32_bf16(a, b1, acc1, 0, 0, 0);
    }

    const int col0 = ct0 * 16 + (lane & 15);
    const int rbase = (lane >> 4) * 4;
    const float bb0 = base_b[col0];
    const float bb1 = base_b[col0 + 16];
#pragma unroll
    for (int r = 0; r < 4; ++r) {
        const int row = nodeBase + rbase + r;
        const float di = dis[row];
        Ssc[(size_t)row * 128 + col0]      = f2bf((acc0[r] + bb0) * di);
        Ssc[(size_t)row * 128 + col0 + 16] = f2bf((acc1[r] + bb1) * di);
    }
}

// ---------------- aggregation via per-node LDS bitmask (dedup, deterministic) ----------------
__global__ __launch_bounds__(128) void aggregate_kernel(
    const int* __restrict__ start, const int* __restrict__ adj,
    const ushort* __restrict__ Ssc, const float* __restrict__ dis,
    const float* __restrict__ bias, float* __restrict__ out) {
    __shared__ uint32 mask[512];
    __shared__ ushort lst[4096];
    __shared__ int cnts[128];
    __shared__ float part[2][128];
    const int t = threadIdx.x;
    const int i = blockIdx.x;

#pragma unroll
    for (int q = 0; q < 4; ++q) mask[t * 4 + q] = 0;
    __syncthreads();
    const int s0 = start[i];
    const int len = start[i + 1] - s0;
    for (int p = t; p < len; p += 128) {
        int j = adj[s0 + p];
        atomicOr(&mask[j >> 5], 1u << (j & 31));
    }
    __syncthreads();

    uint32 wsv[4];
#pragma unroll
    for (int q = 0; q < 4; ++q) wsv[q] = mask[t * 4 + q];
    int myc = __popc(wsv[0]) + __popc(wsv[1]) + __popc(wsv[2]) + __popc(wsv[3]);
    cnts[t] = myc;
    __syncthreads();
#pragma unroll
    for (int off = 1; off < 128; off <<= 1) {
        int v = cnts[t];
        int add = (t >= off) ? cnts[t - off] : 0;
        __syncthreads();
        cnts[t] = v + add;
        __syncthreads();
    }
    int st = cnts[t] - myc;
    int total = cnts[127];
    if (total > 4096) total = 4096;

    int pos = st;
#pragma unroll
    for (int q = 0; q < 4; ++q) {
        uint32 wbits = wsv[q];
        int cbase = t * 128 + q * 32;
        while (wbits) {
            int b = __ffs(wbits) - 1;
            wbits &= wbits - 1;
            if (pos < 4096) lst[pos] = (ushort)(cbase + b);
            ++pos;
        }
    }
    __syncthreads();

    const int lane = t & 63;
    const int wv = t >> 6;
    const uint32* S32 = (const uint32*)Ssc;          // row stride 64 uints
    float a0 = 0.f, a1 = 0.f;
    int idx = wv;
    for (; idx + 6 < total; idx += 8) {
        int j0 = lst[idx], j1 = lst[idx + 2], j2 = lst[idx + 4], j3 = lst[idx + 6];
        uint32 u0 = S32[(size_t)j0 * 64 + lane];
        uint32 u1 = S32[(size_t)j1 * 64 + lane];
        uint32 u2 = S32[(size_t)j2 * 64 + lane];
        uint32 u3 = S32[(size_t)j3 * 64 + lane];
        a0 += (bflo(u0) + bflo(u1)) + (bflo(u2) + bflo(u3));
        a1 += (bfhi(u0) + bfhi(u1)) + (bfhi(u2) + bfhi(u3));
    }
    for (; idx < total; idx += 2) {
        uint32 u = S32[(size_t)lst[idx] * 64 + lane];
        a0 += bflo(u);
        a1 += bfhi(u);
    }
    part[wv][lane * 2]     = a0;
    part[wv][lane * 2 + 1] = a1;
    __syncthreads();

    float v = part[0][t] + part[1][t];
    out[(size_t)i * 128 + t] = v * dis[i] + bias[t];
}

extern "C" void kernel_launch(void* const* d_in, const int* in_sizes, int n_in,
                              void* d_out, int out_size, void* d_ws, size_t ws_size,
                              hipStream_t stream) {
    const float* x        = (const float*)d_in[0];
    const int*   ei       = (const int*)d_in[1];
    const float* ln_gamma = (const float*)d_in[2];
    const float* ln_beta  = (const float*)d_in[3];
    const float* spline_w = (const float*)d_in[4];
    const float* base_w   = (const float*)d_in[5];
    const float* base_b   = (const float*)d_in[6];
    const float* bias     = (const float*)d_in[7];
    float* out = (float*)d_out;

    char* ws = (char*)d_ws;
    const size_t CNT_OFF   = 0;              //    65,536 B
    const size_t START_OFF = 65536;          //    65,600 B -> pad to 131,072
    const size_t ADJ_OFF   = 196608;         // 4,194,304 B (2E ints)
    const size_t WP_OFF    = 4390912;        //   294,912 B
    const size_t DIS_OFF   = 4685824;        //    65,536 B
    const size_t SSC_OFF   = 4751360;        // 4,194,304 B
    const size_t NEEDED    = 8945664;
    if (ws_size < NEEDED) return;

    int*    cnt   = (int*)(ws + CNT_OFF);
    int*    start = (int*)(ws + START_OFF);
    int*    adj   = (int*)(ws + ADJ_OFF);
    ushort* Wp    = (ushort*)(ws + WP_OFF);
    float*  dis   = (float*)(ws + DIS_OFF);
    ushort* Ssc   = (ushort*)(ws + SSC_OFF);

    hipMemsetAsync(cnt, 0, (size_t)N_NODES * 4, stream);
    transw_kernel<<<576, 256, 0, stream>>>(spline_w, base_w, Wp);
    hist_kernel<<<NE / 256, 256, 0, stream>>>(ei, cnt);
    scan_kernel<<<1, 1024, 0, stream>>>(cnt, start);
    fill_kernel<<<NE / 256, 256, 0, stream>>>(ei, start, cnt, adj);
    deg_kernel<<<N_NODES / 4, 256, 0, stream>>>(start, adj, dis);
    support_kernel<<<N_NODES / 16, 256, 0, stream>>>(x, ln_gamma, ln_beta, Wp,
                                                     base_b, dis, Ssc);
    aggregate_kernel<<<N_NODES, 128, 0, stream>>>(start, adj, Ssc, dis, bias, out);
}

// Round 4
// 89.306 us; speedup vs baseline: 1.8754x; 1.8754x over previous
//
#include <hip/hip_runtime.h>

#define N_NODES 16384
#define NE 524288
#define WORDS 512          // bitmask words per node row
#define KDIM 1152          // IN*NG + IN
#define KSTEPS 36          // 1152 / 32
#define NBUCK 512          // buckets of 32 nodes
#define BCAP 2816          // per-bucket entry capacity (mean 2048, sigma~45)
#define MROW 516           // padded LDS row stride (words) to break bank conflicts

typedef unsigned int uint32;
typedef unsigned short ushort;
typedef __attribute__((ext_vector_type(8))) short bf16x8;
typedef __attribute__((ext_vector_type(4))) float f32x4;

__device__ __forceinline__ ushort f2bf(float f) {
    unsigned u = __float_as_uint(f);
    unsigned r = (u + 0x7fffu + ((u >> 16) & 1u)) >> 16;
    return (ushort)r;
}
__device__ __forceinline__ float bflo(uint32 u) {
    return __uint_as_float(u << 16);
}
__device__ __forceinline__ float bfhi(uint32 u) {
    return __uint_as_float(u & 0xffff0000u);
}

// ---------------- weight pack into MFMA B-fragment order + cursor init ----------------
__global__ __launch_bounds__(256) void transw_kernel(
    const float* __restrict__ sw, const float* __restrict__ bw,
    ushort* __restrict__ Wp, int* __restrict__ cursor) {
    int idx = blockIdx.x * 256 + threadIdx.x;      // 0 .. 147455
    if (idx < NBUCK) cursor[idx] = idx * BCAP;
    int i  = idx & 7;
    int l  = (idx >> 3) & 63;
    int ct = (idx >> 9) & 7;
    int kk = idx >> 12;
    int k   = kk * 32 + ((l >> 4) << 3) + i;
    int col = ct * 16 + (l & 15);
    float v = (k < 1024) ? sw[col * 1024 + k] : bw[col * 128 + (k - 1024)];
    Wp[idx] = f2bf(v);
}

// ---------------- bin directed edges into 512 node-range buckets ----------------
// 512 blocks x 256 threads x 4 edges (8 directed entries) each
__global__ __launch_bounds__(256) void sort_kernel(
    const int* __restrict__ ei, int* __restrict__ cursor,
    uint32* __restrict__ ebuf) {
    __shared__ int hcnt[NBUCK];
    __shared__ int gbase[NBUCK];
    const int t = threadIdx.x;
    hcnt[t] = 0;
    hcnt[t + 256] = 0;
    __syncthreads();

    int bk[8], sl[8];
    uint32 pk[8];
#pragma unroll
    for (int k = 0; k < 4; ++k) {
        int e = blockIdx.x * 1024 + k * 256 + t;
        int a = ei[e];
        int b = ei[NE + e];
        bk[2 * k]     = a >> 5;
        pk[2 * k]     = ((uint32)(a & 31) << 14) | (uint32)b;
        bk[2 * k + 1] = b >> 5;
        pk[2 * k + 1] = ((uint32)(b & 31) << 14) | (uint32)a;
        sl[2 * k]     = atomicAdd(&hcnt[bk[2 * k]], 1);
        sl[2 * k + 1] = atomicAdd(&hcnt[bk[2 * k + 1]], 1);
    }
    __syncthreads();
    for (int q = t; q < NBUCK; q += 256) {
        int c = hcnt[q];
        gbase[q] = c ? atomicAdd(cursor + q, c) : 0;
    }
    __syncthreads();
#pragma unroll
    for (int k = 0; k < 8; ++k) {
        int idx = gbase[bk[k]] + sl[k];
        if (idx < (bk[k] + 1) * BCAP)
            ebuf[idx] = pk[k];
    }
}

// ---------------- per-bucket LDS bitmask: dedup degree + full bitmask dump ----------------
// 512 blocks (one per 32-node bucket) x 256 threads
__global__ __launch_bounds__(256) void degb_kernel(
    const int* __restrict__ cursor, const uint32* __restrict__ ebuf,
    float* __restrict__ dis, uint32* __restrict__ bm) {
    __shared__ uint32 mask[32 * MROW];              // 66,048 B
    const int t = threadIdx.x;
    const int bkt = blockIdx.x;
    for (int i = t; i < 32 * MROW; i += 256) mask[i] = 0;
    __syncthreads();

    int cnt = cursor[bkt] - bkt * BCAP;
    if (cnt > BCAP) cnt = BCAP;
    const uint32* eb = ebuf + (size_t)bkt * BCAP;
    for (int p = t; p < cnt; p += 256) {
        uint32 e = eb[p];
        int ln = e >> 14;
        int nb = e & 16383;
        atomicOr(&mask[ln * MROW + (nb >> 5)], 1u << (nb & 31));
    }
    __syncthreads();

    // dedup'd degree: 8 threads per node, 2-way-max LDS banks
    {
        const int node = t >> 3;
        const int sub = t & 7;
        const uint32* row = &mask[node * MROW];
        int c = 0;
#pragma unroll
        for (int k = 0; k < 64; ++k) c += __popc(row[sub + k * 8]);
#pragma unroll
        for (int o = 1; o < 8; o <<= 1) c += __shfl_xor(c, o);
        if (sub == 0) dis[bkt * 32 + node] = rsqrtf((float)c);
    }

    // coalesced dump (full overwrite -> no global clear ever needed)
    uint32* gout = bm + (size_t)bkt * 32 * WORDS;
#pragma unroll 4
    for (int k = 0; k < 64; ++k) {
        int g = t + k * 256;
        gout[g] = mask[(g >> 9) * MROW + (g & 511)];
    }
}

// ---------------- fused FastKAN support (bf16 MFMA), pre-scaled by dis ----------------
__global__ __launch_bounds__(256) void support_kernel(
    const float* __restrict__ x, const float* __restrict__ gamma,
    const float* __restrict__ beta, const ushort* __restrict__ Wp,
    const float* __restrict__ base_b, const float* __restrict__ dis,
    ushort* __restrict__ Ssc) {
    __shared__ ushort Bs[16][KDIM];                 // 36864 B
    const int t = threadIdx.x;
    const int lane = t & 63;
    const int w = t >> 6;
    const int nodeBase = blockIdx.x * 16;

    const float g0 = gamma[lane], g1 = gamma[lane + 64];
    const float be0 = beta[lane], be1 = beta[lane + 64];

    for (int n = w * 4; n < w * 4 + 4; ++n) {
        const int row = nodeBase + n;
        float f0 = x[(size_t)row * 128 + lane];
        float f1 = x[(size_t)row * 128 + lane + 64];
        float s = f0 + f1;
#pragma unroll
        for (int o = 32; o; o >>= 1) s += __shfl_xor(s, o);
        float mu = s * 0.0078125f;
        float d0 = f0 - mu, d1 = f1 - mu;
        float v = d0 * d0 + d1 * d1;
#pragma unroll
        for (int o = 32; o; o >>= 1) v += __shfl_xor(v, o);
        float rstd = rsqrtf(v * 0.0078125f + 1e-5f);
        float h0 = d0 * rstd * g0 + be0;
        float h1 = d1 * rstd * g1 + be1;
        ushort pk0[8] __attribute__((aligned(16)));
        ushort pk1[8] __attribute__((aligned(16)));
#pragma unroll
        for (int g = 0; g < 8; ++g) {
            float gv = -2.0f + (float)g * (4.0f / 7.0f);
            float z0 = (h0 - gv) * 1.75f;
            float z1 = (h1 - gv) * 1.75f;
            pk0[g] = f2bf(__expf(-z0 * z0));
            pk1[g] = f2bf(__expf(-z1 * z1));
        }
        *reinterpret_cast<uint4*>(&Bs[n][lane * 8]) =
            *reinterpret_cast<const uint4*>(pk0);
        *reinterpret_cast<uint4*>(&Bs[n][(lane + 64) * 8]) =
            *reinterpret_cast<const uint4*>(pk1);
        Bs[n][1024 + lane]      = f2bf(f0 / (1.0f + __expf(-f0)));
        Bs[n][1024 + lane + 64] = f2bf(f1 / (1.0f + __expf(-f1)));
    }
    __syncthreads();

    const int ct0 = w * 2;
    f32x4 acc0 = {0.f, 0.f, 0.f, 0.f};
    f32x4 acc1 = {0.f, 0.f, 0.f, 0.f};
    const ushort* ArowBase = &Bs[lane & 15][(lane >> 4) * 8];
    const bf16x8* Wv = (const bf16x8*)Wp;
#pragma unroll 4
    for (int kk = 0; kk < KSTEPS; ++kk) {
        bf16x8 a = *reinterpret_cast<const bf16x8*>(ArowBase + kk * 32);
        bf16x8 b0 = Wv[(size_t)(kk * 8 + ct0) * 64 + lane];
        bf16x8 b1 = Wv[(size_t)(kk * 8 + ct0 + 1) * 64 + lane];
        acc0 = __builtin_amdgcn_mfma_f32_16x16x32_bf16(a, b0, acc0, 0, 0, 0);
        acc1 = __builtin_amdgcn_mfma_f32_16x16x32_bf16(a, b1, acc1, 0, 0, 0);
    }

    const int col0 = ct0 * 16 + (lane & 15);
    const int rbase = (lane >> 4) * 4;
    const float bb0 = base_b[col0];
    const float bb1 = base_b[col0 + 16];
#pragma unroll
    for (int r = 0; r < 4; ++r) {
        const int row = nodeBase + rbase + r;
        const float di = dis[row];
        Ssc[(size_t)row * 128 + col0]      = f2bf((acc0[r] + bb0) * di);
        Ssc[(size_t)row * 128 + col0 + 16] = f2bf((acc1[r] + bb1) * di);
    }
}

// ---------------- aggregation: out[i] = dis_i * sum Ssc[nbr] + bias ----------------
__global__ __launch_bounds__(128) void aggregate_kernel(
    const uint32* __restrict__ bm, const ushort* __restrict__ Ssc,
    const float* __restrict__ dis, const float* __restrict__ bias,
    float* __restrict__ out) {
    __shared__ ushort lst[4096];
    __shared__ int cnts[128];
    __shared__ float part[2][128];
    const int t = threadIdx.x;
    const int i = blockIdx.x;

    uint4 w4 = ((const uint4*)(bm + (size_t)i * WORDS))[t];
    uint32 wsv[4] = {w4.x, w4.y, w4.z, w4.w};
    int myc = __popc(wsv[0]) + __popc(wsv[1]) + __popc(wsv[2]) + __popc(wsv[3]);
    cnts[t] = myc;
    __syncthreads();
#pragma unroll
    for (int off = 1; off < 128; off <<= 1) {
        int v = cnts[t];
        int add = (t >= off) ? cnts[t - off] : 0;
        __syncthreads();
        cnts[t] = v + add;
        __syncthreads();
    }
    int st = cnts[t] - myc;
    int total = cnts[127];
    if (total > 4096) total = 4096;

    int pos = st;
#pragma unroll
    for (int q = 0; q < 4; ++q) {
        uint32 wbits = wsv[q];
        int cbase = t * 128 + q * 32;
        while (wbits) {
            int b = __ffs(wbits) - 1;
            wbits &= wbits - 1;
            if (pos < 4096) lst[pos] = (ushort)(cbase + b);
            ++pos;
        }
    }
    __syncthreads();

    const int lane = t & 63;
    const int wv = t >> 6;
    const uint32* S32 = (const uint32*)Ssc;          // row stride 64 uints
    float a0 = 0.f, a1 = 0.f;
    int idx = wv;
    for (; idx + 6 < total; idx += 8) {
        int j0 = lst[idx], j1 = lst[idx + 2], j2 = lst[idx + 4], j3 = lst[idx + 6];
        uint32 u0 = S32[(size_t)j0 * 64 + lane];
        uint32 u1 = S32[(size_t)j1 * 64 + lane];
        uint32 u2 = S32[(size_t)j2 * 64 + lane];
        uint32 u3 = S32[(size_t)j3 * 64 + lane];
        a0 += (bflo(u0) + bflo(u1)) + (bflo(u2) + bflo(u3));
        a1 += (bfhi(u0) + bfhi(u1)) + (bfhi(u2) + bfhi(u3));
    }
    for (; idx < total; idx += 2) {
        uint32 u = S32[(size_t)lst[idx] * 64 + lane];
        a0 += bflo(u);
        a1 += bfhi(u);
    }
    part[wv][lane * 2]     = a0;
    part[wv][lane * 2 + 1] = a1;
    __syncthreads();

    float v = part[0][t] + part[1][t];
    out[(size_t)i * 128 + t] = v * dis[i] + bias[t];
}

extern "C" void kernel_launch(void* const* d_in, const int* in_sizes, int n_in,
                              void* d_out, int out_size, void* d_ws, size_t ws_size,
                              hipStream_t stream) {
    const float* x        = (const float*)d_in[0];
    const int*   ei       = (const int*)d_in[1];
    const float* ln_gamma = (const float*)d_in[2];
    const float* ln_beta  = (const float*)d_in[3];
    const float* spline_w = (const float*)d_in[4];
    const float* base_w   = (const float*)d_in[5];
    const float* base_b   = (const float*)d_in[6];
    const float* bias     = (const float*)d_in[7];
    float* out = (float*)d_out;

    char* ws = (char*)d_ws;
    const size_t CUR_OFF = 0;              //     4,096 B (512 cursors, padded)
    const size_t WP_OFF  = 4096;           //   294,912 B
    const size_t DIS_OFF = 299008;         //    65,536 B
    const size_t BM_OFF  = 364544;         // 33,554,432 B
    const size_t ES_OFF  = 33918976;       // max(ebuf 5,767,168 ; Ssc 4,194,304)
    const size_t NEEDED  = 39686144;
    if (ws_size < NEEDED) return;

    int*    cursor = (int*)(ws + CUR_OFF);
    ushort* Wp     = (ushort*)(ws + WP_OFF);
    float*  dis    = (float*)(ws + DIS_OFF);
    uint32* bm     = (uint32*)(ws + BM_OFF);
    uint32* ebuf   = (uint32*)(ws + ES_OFF);       // dead after degb_kernel
    ushort* Ssc    = (ushort*)(ws + ES_OFF);       // written by support afterwards

    transw_kernel<<<576, 256, 0, stream>>>(spline_w, base_w, Wp, cursor);
    sort_kernel<<<512, 256, 0, stream>>>(ei, cursor, ebuf);
    degb_kernel<<<NBUCK, 256, 0, stream>>>(cursor, ebuf, dis, bm);
    support_kernel<<<N_NODES / 16, 256, 0, stream>>>(x, ln_gamma, ln_beta, Wp,
                                                     base_b, dis, Ssc);
    aggregate_kernel<<<N_NODES, 128, 0, stream>>>(bm, Ssc, dis, bias, out);
}